// Round 5
// baseline (2064.818 us; speedup 1.0000x reference)
//
#include <hip/hip_runtime.h>
#include <hip/hip_bf16.h>
#include <math.h>

// Problem constants (match reference)
#define B_   64
#define P_   150   // n_pred (rows)
#define T_   150   // n_true (cols)
#define C_   81
#define NOOBJ 80

// ---------------------------------------------------------------------------
// Kernel 1: cost matrix [B, P, T] in f32
// ---------------------------------------------------------------------------
__global__ void cost_kernel(const float* __restrict__ prob,
                            const float* __restrict__ pbox,
                            const float* __restrict__ labels,
                            float* __restrict__ cost) {
    int idx = blockIdx.x * blockDim.x + threadIdx.x;
    const int total = B_ * P_ * T_;
    if (idx >= total) return;
    int t  = idx % T_;
    int p  = (idx / T_) % P_;
    int b  = idx / (P_ * T_);

    const float* lb5 = labels + ((size_t)b * T_ + t) * 5;
    const float inv = 1.0f / 320.0f;
    float lcx = lb5[0] * inv, lcy = lb5[1] * inv, lw = lb5[2] * inv, lh = lb5[3] * inv;
    int cls = (int)lb5[4];

    const float* pb = pbox + ((size_t)b * P_ + p) * 4;
    float pcx = pb[0], pcy = pb[1], pw = pb[2], ph = pb[3];

    float nll = -logf(prob[((size_t)b * P_ + p) * C_ + cls]);

    float l1 = 0.25f * (fabsf(pcx - lcx) + fabsf(pcy - lcy) +
                        fabsf(pw - lw)   + fabsf(ph - lh));

    float px0 = pcx - 0.5f * pw, py0 = pcy - 0.5f * ph;
    float px1 = pcx + 0.5f * pw, py1 = pcy + 0.5f * ph;
    float lx0 = lcx - 0.5f * lw, ly0 = lcy - 0.5f * lh;
    float lx1 = lcx + 0.5f * lw, ly1 = lcy + 0.5f * lh;

    float ltx = fmaxf(px0, lx0), lty = fmaxf(py0, ly0);
    float rbx = fminf(px1, lx1), rby = fminf(py1, ly1);
    float iw = fmaxf(rbx - ltx, 0.f), ih = fmaxf(rby - lty, 0.f);
    float inter = iw * ih;
    float ap = (px1 - px0) * (py1 - py0);
    float al = (lx1 - lx0) * (ly1 - ly0);
    float un = ap + al - inter;
    float iou = inter / (un + 1e-7f);

    float cx0 = fminf(px0, lx0), cy0 = fminf(py0, ly0);
    float cx1 = fmaxf(px1, lx1), cy1 = fmaxf(py1, ly1);
    float cw = fmaxf(cx1 - cx0, 0.f), ch = fmaxf(cy1 - cy0, 0.f);
    float enc = cw * ch;
    float giou = iou - (enc - un) / (enc + 1e-7f);
    float gl = 1.0f - giou;

    float mask = (cls != NOOBJ) ? 1.0f : 0.0f;
    cost[idx] = nll + (5.0f * l1 + 2.0f * gl) * mask;
}

// ---------------------------------------------------------------------------
// Kernel 2: LAPJV-style Hungarian, one wave per batch, register-resident.
//  Stage A: column reduction (v[j]=min_i c[i,j]) + greedy column assignment
//  Stage B: augmenting row reduction, 2 passes (LAPJV), chain-capped
//  Stage C: shortest-augmenting-path phases for remaining free rows (e-maxx)
//  Invariant maintained in every stage: rc[i,j]=c-u[i]-v[j] >= 0 for all
//  assigned rows (==0 on matched edges) -> final matching is the exact
//  optimum -> equals reference (unique optimum for continuous random data).
// ---------------------------------------------------------------------------
#define SM_U      (P_ * T_ * 4)           // after 90000 B cost tile (8B aligned)
#define SM_TOTAL  (SM_U + 152 * 8)

__device__ __forceinline__ unsigned ord32(float f) {
    unsigned bits = __float_as_uint(f);
    return (bits & 0x80000000u) ? ~bits : (bits | 0x80000000u);
}

#define DPPMIN(x, ctrl)                                                          \
    do {                                                                         \
        unsigned _t = (unsigned)__builtin_amdgcn_update_dpp(                     \
            (int)(x), (int)(x), (ctrl), 0xF, 0xF, false);                        \
        (x) = (_t < (x)) ? _t : (x);                                             \
    } while (0)

__device__ __forceinline__ int sel3i(int s, int a, int b, int c) {
    return s == 0 ? a : (s == 1 ? b : c);
}

// wave-wide exact f64 argmin; payload tie-break = smaller pay on exact ties
__device__ __forceinline__ void wave_argmin(double lval, int lpay,
                                            double* oval, int* opay) {
    float kf = (float)lval + 0.0f;
    unsigned key = ord32(kf);
    unsigned x = key;
    DPPMIN(x, 0x111); DPPMIN(x, 0x112); DPPMIN(x, 0x114);
    DPPMIN(x, 0x118); DPPMIN(x, 0x142); DPPMIN(x, 0x143);
    unsigned kmin = (unsigned)__builtin_amdgcn_readlane((int)x, 63);
    unsigned long long cm = __ballot(key == kmin);
    if (__popcll(cm) == 1) {
        int L = (int)__builtin_ctzll(cm);
        int hi = __builtin_amdgcn_readlane(__double2hiint(lval), L);
        int lo = __builtin_amdgcn_readlane(__double2loint(lval), L);
        *oval = __hiloint2double(hi, lo);
        *opay = __builtin_amdgcn_readlane(lpay, L);
    } else {
        double bv = __builtin_inf(); int bp = 0x7FFFFFFF;
        unsigned long long m = cm;
        while (m) {
            int L = (int)__builtin_ctzll(m); m &= m - 1;
            int hi = __builtin_amdgcn_readlane(__double2hiint(lval), L);
            int lo = __builtin_amdgcn_readlane(__double2loint(lval), L);
            double dv = __hiloint2double(hi, lo);
            int dp = __builtin_amdgcn_readlane(lpay, L);
            if (dv < bv || (dv == bv && dp < bp)) { bv = dv; bp = dp; }
        }
        *oval = bv; *opay = bp;
    }
}

__global__ __launch_bounds__(64) void hungarian_kernel(const float* __restrict__ cost,
                                                       int* __restrict__ assign) {
    const int b = blockIdx.x;
    const int lane = threadIdx.x;
    const float* Cg = cost + (size_t)b * (P_ * T_);

    extern __shared__ char smem[];
    float*  cl = (float*)smem;             // [150*150] f32 cost tile
    double* u  = (double*)(smem + SM_U);   // [151] f64 row duals

    for (int i4 = lane; i4 < (P_ * T_) / 4; i4 += 64)
        ((float4*)cl)[i4] = ((const float4*)Cg)[i4];
    for (int r = lane; r <= P_; r += 64) u[r] = 0.0;
    __syncthreads();

    // per-lane column slots
    const int ja = 1 + lane;            // slot 0: cols 1..64
    const int jb = 65 + lane;           // slot 1: cols 65..128
    const int jc = 129 + lane;          // slot 2: cols 129..150 (lanes 0..21)
    const bool va2 = (jc <= T_);
    const int jcs = va2 ? jc : T_;      // safe address for slot-2 loads

    const double INF = __builtin_inf();

    // ---- Stage A: column reduction with argmin tracking -------------------
    float m0 = cl[ja - 1], m1 = cl[jb - 1], m2 = cl[jcs - 1];
    int i1a = 1, i1b = 1, i1c = 1;      // argmin row per column (first on tie)
    #pragma unroll 4
    for (int r = 2; r <= P_; ++r) {
        int rb_ = (r - 1) * T_;
        float t0 = cl[rb_ + ja - 1], t1 = cl[rb_ + jb - 1], t2 = cl[rb_ + jcs - 1];
        if (t0 < m0) { m0 = t0; i1a = r; }
        if (t1 < m1) { m1 = t1; i1b = r; }
        if (t2 < m2) { m2 = t2; i1c = r; }
    }
    double v0 = (double)m0, v1 = (double)m1, v2 = va2 ? (double)m2 : 0.0;
    int pa = 0, pb = 0, pc = 0;         // p[j]: row matched to col (0 = none)

    // free-row mask: row r <-> lane (r-1)&63, bit (r-1)>>6
    int frm = (lane < 22) ? 7 : 3;

    // greedy column assignment (serial over columns, wave-uniform)
    for (int j = 1; j <= T_; ++j) {
        int sl = (j - 1) >> 6, ol = (j - 1) & 63;
        int i1 = __builtin_amdgcn_readlane(sel3i(sl, i1a, i1b, i1c), ol);
        int rl = (i1 - 1) & 63, rs = (i1 - 1) >> 6;
        int fm = __builtin_amdgcn_readlane(frm, rl);
        if (fm & (1 << rs)) {
            if (lane == ol) {
                if (sl == 0) pa = i1; else if (sl == 1) pb = i1; else pc = i1;
            }
            if (lane == rl) frm &= ~(1 << rs);
        }
    }

    // ---- Stage B: augmenting row reduction (2 passes, LAPJV) --------------
    for (int pass = 0; pass < 2; ++pass) {
        for (int irow = 1; irow <= P_; ++irow) {
            {
                int rl = (irow - 1) & 63, rs = (irow - 1) >> 6;
                int fm = __builtin_amdgcn_readlane(frm, rl);
                if (!(fm & (1 << rs))) continue;
            }
            int i = irow;
            for (int guard = 0; guard < 256; ++guard) {
                int base = (i - 1) * T_ - 1;
                float f0 = cl[base + ja], f1 = cl[base + jb], f2 = cl[base + jcs];
                double r0 = (double)f0 - v0;
                double r1 = (double)f1 - v1;
                double r2 = va2 ? ((double)f2 - v2) : INF;
                // lane-local first/second min with columns (ascending-j ties)
                double lm1, lm2; int lj1, lj2;
                if (r0 <= r1) { lm1 = r0; lj1 = ja; lm2 = r1; lj2 = jb; }
                else          { lm1 = r1; lj1 = jb; lm2 = r0; lj2 = ja; }
                if (r2 < lm1)      { lm2 = lm1; lj2 = lj1; lm1 = r2; lj1 = jc; }
                else if (r2 < lm2) { lm2 = r2; lj2 = jc; }

                double umin; int j1;
                wave_argmin(lm1, lj1, &umin, &j1);
                double s1 = (lj1 == j1) ? lm2 : lm1;
                int    sj = (lj1 == j1) ? lj2 : lj1;
                double usub; int j2;
                wave_argmin(s1, sj, &usub, &j2);

                bool strict = (umin < usub);
                int jt = j1;
                if (strict) {
                    double d = usub - umin;
                    if (lane == ((j1 - 1) & 63)) {
                        int sl = (j1 - 1) >> 6;
                        if (sl == 0) v0 -= d; else if (sl == 1) v1 -= d; else v2 -= d;
                    }
                } else {
                    int sl = (j1 - 1) >> 6, ol = (j1 - 1) & 63;
                    int pj1 = __builtin_amdgcn_readlane(sel3i(sl, pa, pb, pc), ol);
                    if (pj1 != 0) jt = j2;
                }
                int slt = (jt - 1) >> 6, olt = (jt - 1) & 63;
                int k = __builtin_amdgcn_readlane(sel3i(slt, pa, pb, pc), olt);
                // assign i -> jt
                if (lane == olt) {
                    if (slt == 0) pa = i; else if (slt == 1) pb = i; else pc = i;
                }
                if (lane == 0) u[i] = strict ? usub : umin;   // rc[i,jt] = 0
                { int rl = (i - 1) & 63, rs = (i - 1) >> 6;
                  if (lane == rl) frm &= ~(1 << rs); }
                if (k != 0) {
                    int rl = (k - 1) & 63, rs = (k - 1) >> 6;
                    if (lane == rl) frm |= (1 << rs);
                }
                if (k == 0 || !strict) break;   // tie-bump deferred (LAPJV)
                i = k;                          // strict-bump reprocessed now
            }
        }
    }

    // ---- Stage C: SAP phases for remaining free rows (e-maxx, unchanged) --
    for (int i = 1; i <= P_; ++i) {
        {
            int rl = (i - 1) & 63, rs = (i - 1) >> 6;
            int fm = __builtin_amdgcn_readlane(frm, rl);
            if (!(fm & (1 << rs))) continue;
        }
        double mv0 = INF, mv1 = INF, mv2 = INF;
        int w0 = 0, w1 = 0, w2 = 0;
        int um = va2 ? 0 : 4;           // invalid slot2 marked used
        double ua = 0.0, ub = 0.0, uc = 0.0;   // register u of tree rows
        int ra = 0, rb = 0, rc = 0;
        int j0 = 0;
        int i0cur = i;

        double ui0 = u[i];
        double u_i = ui0;
        int base = (i - 1) * T_ - 1;
        float c0 = cl[base + ja];
        float c1 = cl[base + jb];
        float c2 = cl[base + jcs];

        while (true) {
            if (j0 > 0 && lane == ((j0 - 1) & 63)) {
                int sl = (j0 - 1) >> 6;
                if (sl == 0)      { um |= 1; ua = ui0; ra = i0cur; }
                else if (sl == 1) { um |= 2; ub = ui0; rb = i0cur; }
                else              { um |= 4; uc = ui0; rc = i0cur; }
            }

            double cur0 = ((double)c0 - ui0) - v0;
            double cur1 = ((double)c1 - ui0) - v1;
            double cur2 = ((double)c2 - ui0) - v2;
            if (!(um & 1) && cur0 < mv0) { mv0 = cur0; w0 = j0; }
            if (!(um & 2) && cur1 < mv1) { mv1 = cur1; w1 = j0; }
            if (!(um & 4) && cur2 < mv2) { mv2 = cur2; w2 = j0; }

            double bestv = INF; int bestj = 0x7FFFFFFF; int bestp = 0;
            if (!(um & 1))                { bestv = mv0; bestj = ja; bestp = pa; }
            if (!(um & 2) && mv1 < bestv) { bestv = mv1; bestj = jb; bestp = pb; }
            if (!(um & 4) && mv2 < bestv) { bestv = mv2; bestj = jc; bestp = pc; }

            float kf = (float)bestv + 0.0f;
            unsigned key = ord32(kf);
            unsigned x = key;
            DPPMIN(x, 0x111); DPPMIN(x, 0x112); DPPMIN(x, 0x114);
            DPPMIN(x, 0x118); DPPMIN(x, 0x142); DPPMIN(x, 0x143);
            unsigned kmin = (unsigned)__builtin_amdgcn_readlane((int)x, 63);

            unsigned long long cm = __ballot(key == kmin);
            int j1, pj; double delta;
            int pk = (bestp << 8) | (bestj & 0xFF);
            if (__popcll(cm) == 1) {
                int L = (int)__builtin_ctzll(cm);
                int pkw = __builtin_amdgcn_readlane(pk, L);
                j1 = pkw & 0xFF;
                pj = pkw >> 8;
                int hi = __builtin_amdgcn_readlane(__double2hiint(bestv), L);
                int lo = __builtin_amdgcn_readlane(__double2loint(bestv), L);
                delta = __hiloint2double(hi, lo);
            } else {
                double bv = INF; int bj = 0x7FFFFFFF; int bp = 0;
                unsigned long long m = cm;
                while (m) {
                    int L = (int)__builtin_ctzll(m); m &= m - 1;
                    int hi = __builtin_amdgcn_readlane(__double2hiint(bestv), L);
                    int lo = __builtin_amdgcn_readlane(__double2loint(bestv), L);
                    double dv = __hiloint2double(hi, lo);
                    int dj = __builtin_amdgcn_readlane(bestj, L);
                    int dp = __builtin_amdgcn_readlane(bestp, L);
                    if (dv < bv || (dv == bv && dj < bj)) { bv = dv; bj = dj; bp = dp; }
                }
                j1 = bj; pj = bp; delta = bv;
            }

            int pr = (pj > 0) ? pj : 1;
            double ui_n = u[pr];
            int bn = (pr - 1) * T_ - 1;
            float c0n = cl[bn + ja];
            float c1n = cl[bn + jb];
            float c2n = cl[bn + jcs];

            if (um & 1) { v0 -= delta; ua += delta; } else { mv0 -= delta; }
            if (um & 2) { v1 -= delta; ub += delta; } else { mv1 -= delta; }
            if (va2) {
                if (um & 4) { v2 -= delta; uc += delta; } else { mv2 -= delta; }
            }
            u_i += delta;

            i0cur = pj;
            j0 = j1;
            if (pj == 0) break;
            ui0 = ui_n; c0 = c0n; c1 = c1n; c2 = c2n;
        }

        if (um & 1) u[ra] = ua;
        if (um & 2) u[rb] = ub;
        if (va2 && (um & 4)) u[rc] = uc;
        if (lane == 0) u[i] = u_i;

        int jj = j0;
        while (jj != 0) {
            int sj = (jj - 1) >> 6, lj = (jj - 1) & 63;
            int jn = __shfl(sel3i(sj, w0, w1, w2), lj);
            int rown;
            if (jn == 0) rown = i;
            else {
                int sn = (jn - 1) >> 6, ln = (jn - 1) & 63;
                rown = __shfl(sel3i(sn, pa, pb, pc), ln);
            }
            if (lane == lj) {
                if (sj == 0) pa = rown; else if (sj == 1) pb = rown; else pc = rown;
            }
            jj = jn;
        }
    }

    // extract: col j matched to row p[j]-1; perfect matching covers all rows
    assign[b * P_ + (pa - 1)] = ja - 1;
    assign[b * P_ + (pb - 1)] = jb - 1;
    if (va2) assign[b * P_ + (pc - 1)] = jc - 1;
}

// ---------------------------------------------------------------------------
// Kernel 3: per-i partial loss: mean over (b,k) of cost[b, k, assign_i[k]]
// ---------------------------------------------------------------------------
__global__ void gather_kernel(const float* __restrict__ cost,
                              const int* __restrict__ assign,
                              double* __restrict__ partial) {
    const int i = blockIdx.x;
    const int* a = assign + i * P_;
    double s = 0.0;
    for (int idx = threadIdx.x; idx < B_ * P_; idx += blockDim.x) {
        int b = idx / P_;
        int k = idx % P_;
        s += (double)cost[((size_t)b * P_ + k) * T_ + a[k]];
    }
    __shared__ double red[256];
    red[threadIdx.x] = s;
    __syncthreads();
    for (int off = 128; off >= 1; off >>= 1) {
        if (threadIdx.x < off) red[threadIdx.x] += red[threadIdx.x + off];
        __syncthreads();
    }
    if (threadIdx.x == 0) partial[i] = red[0] / (double)(B_ * P_);
}

// ---------------------------------------------------------------------------
// Kernel 4: final sum (deterministic order) -> f32 scalar
// ---------------------------------------------------------------------------
__global__ void finalize_kernel(const double* __restrict__ partial,
                                float* __restrict__ out) {
    if (threadIdx.x == 0 && blockIdx.x == 0) {
        double s = 0.0;
        for (int i = 0; i < B_; ++i) s += partial[i];
        out[0] = (float)s;
    }
}

// ---------------------------------------------------------------------------
extern "C" void kernel_launch(void* const* d_in, const int* in_sizes, int n_in,
                              void* d_out, int out_size, void* d_ws, size_t ws_size,
                              hipStream_t stream) {
    const float* prob   = (const float*)d_in[0];   // [64,150,81]
    const float* pbox   = (const float*)d_in[1];   // [64,150,4]
    const float* labels = (const float*)d_in[2];   // [64,150,5]
    float* out = (float*)d_out;

    char* ws = (char*)d_ws;
    float*  cost    = (float*) ws;                               // 5,760,000 B
    int*    assign  = (int*)   (ws + (size_t)B_ * P_ * T_ * 4);  // 38,400 B
    double* partial = (double*)(ws + (size_t)B_ * P_ * T_ * 4 + (size_t)B_ * P_ * 4);

    const int total = B_ * P_ * T_;
    cost_kernel<<<(total + 255) / 256, 256, 0, stream>>>(prob, pbox, labels, cost);

    hungarian_kernel<<<B_, 64, SM_TOTAL, stream>>>(cost, assign);

    gather_kernel<<<B_, 256, 0, stream>>>(cost, assign, partial);

    finalize_kernel<<<1, 64, 0, stream>>>(partial, out);
}

// Round 6
// 1013.149 us; speedup vs baseline: 2.0380x; 2.0380x over previous
//
#include <hip/hip_runtime.h>
#include <hip/hip_bf16.h>
#include <math.h>

// Problem constants (match reference)
#define B_   64
#define P_   150   // n_pred (rows)
#define T_   150   // n_true (cols)
#define C_   81
#define NOOBJ 80
#define CHAIN_CAP 4   // ARR: max bump-chain steps before deferring (R5 lesson)

// ---------------------------------------------------------------------------
// Kernel 1: cost matrix [B, P, T] in f32
// ---------------------------------------------------------------------------
__global__ void cost_kernel(const float* __restrict__ prob,
                            const float* __restrict__ pbox,
                            const float* __restrict__ labels,
                            float* __restrict__ cost) {
    int idx = blockIdx.x * blockDim.x + threadIdx.x;
    const int total = B_ * P_ * T_;
    if (idx >= total) return;
    int t  = idx % T_;
    int p  = (idx / T_) % P_;
    int b  = idx / (P_ * T_);

    const float* lb5 = labels + ((size_t)b * T_ + t) * 5;
    const float inv = 1.0f / 320.0f;
    float lcx = lb5[0] * inv, lcy = lb5[1] * inv, lw = lb5[2] * inv, lh = lb5[3] * inv;
    int cls = (int)lb5[4];

    const float* pb = pbox + ((size_t)b * P_ + p) * 4;
    float pcx = pb[0], pcy = pb[1], pw = pb[2], ph = pb[3];

    float nll = -logf(prob[((size_t)b * P_ + p) * C_ + cls]);

    float l1 = 0.25f * (fabsf(pcx - lcx) + fabsf(pcy - lcy) +
                        fabsf(pw - lw)   + fabsf(ph - lh));

    float px0 = pcx - 0.5f * pw, py0 = pcy - 0.5f * ph;
    float px1 = pcx + 0.5f * pw, py1 = pcy + 0.5f * ph;
    float lx0 = lcx - 0.5f * lw, ly0 = lcy - 0.5f * lh;
    float lx1 = lcx + 0.5f * lw, ly1 = lcy + 0.5f * lh;

    float ltx = fmaxf(px0, lx0), lty = fmaxf(py0, ly0);
    float rbx = fminf(px1, lx1), rby = fminf(py1, ly1);
    float iw = fmaxf(rbx - ltx, 0.f), ih = fmaxf(rby - lty, 0.f);
    float inter = iw * ih;
    float ap = (px1 - px0) * (py1 - py0);
    float al = (lx1 - lx0) * (ly1 - ly0);
    float un = ap + al - inter;
    float iou = inter / (un + 1e-7f);

    float cx0 = fminf(px0, lx0), cy0 = fminf(py0, ly0);
    float cx1 = fmaxf(px1, lx1), cy1 = fmaxf(py1, ly1);
    float cw = fmaxf(cx1 - cx0, 0.f), ch = fmaxf(cy1 - cy0, 0.f);
    float enc = cw * ch;
    float giou = iou - (enc - un) / (enc + 1e-7f);
    float gl = 1.0f - giou;

    float mask = (cls != NOOBJ) ? 1.0f : 0.0f;
    cost[idx] = nll + (5.0f * l1 + 2.0f * gl) * mask;
}

// ---------------------------------------------------------------------------
// Kernel 2: LAPJV-style Hungarian, one wave per batch, register-resident.
//  Stage A: column reduction + greedy column assignment
//  Stage B: augmenting row reduction, 2 passes, CHAIN-CAPPED (R5 post-mortem:
//           unbounded chains churned ~3300 steps; cap=4 bounds it; deferring
//           the bumped row keeps rc>=0 since v only decreases afterwards)
//  Stage C: shortest-augmenting-path phases for remaining free rows
//  Invariant in every stage: rc[i,j]=c-u[i]-v[j] >= 0 for assigned rows,
//  ==0 on matched edges -> exact optimum -> equals reference (unique optimum
//  for continuous random data; validated absmax=0 in R2-R5).
// ---------------------------------------------------------------------------
#define SM_U      (P_ * T_ * 4)           // after 90000 B cost tile (8B aligned)
#define SM_TOTAL  (SM_U + 152 * 8)

__device__ __forceinline__ unsigned ord32(float f) {
    unsigned bits = __float_as_uint(f);
    return (bits & 0x80000000u) ? ~bits : (bits | 0x80000000u);
}

#define DPPMIN(x, ctrl)                                                          \
    do {                                                                         \
        unsigned _t = (unsigned)__builtin_amdgcn_update_dpp(                     \
            (int)(x), (int)(x), (ctrl), 0xF, 0xF, false);                        \
        (x) = (_t < (x)) ? _t : (x);                                             \
    } while (0)

__device__ __forceinline__ int sel3i(int s, int a, int b, int c) {
    return s == 0 ? a : (s == 1 ? b : c);
}

// wave-wide exact f64 argmin; payload tie-break = smaller pay on exact ties
__device__ __forceinline__ void wave_argmin(double lval, int lpay,
                                            double* oval, int* opay) {
    float kf = (float)lval + 0.0f;
    unsigned key = ord32(kf);
    unsigned x = key;
    DPPMIN(x, 0x111); DPPMIN(x, 0x112); DPPMIN(x, 0x114);
    DPPMIN(x, 0x118); DPPMIN(x, 0x142); DPPMIN(x, 0x143);
    unsigned kmin = (unsigned)__builtin_amdgcn_readlane((int)x, 63);
    unsigned long long cm = __ballot(key == kmin);
    if (__popcll(cm) == 1) {
        int L = (int)__builtin_ctzll(cm);
        int hi = __builtin_amdgcn_readlane(__double2hiint(lval), L);
        int lo = __builtin_amdgcn_readlane(__double2loint(lval), L);
        *oval = __hiloint2double(hi, lo);
        *opay = __builtin_amdgcn_readlane(lpay, L);
    } else {
        double bv = __builtin_inf(); int bp = 0x7FFFFFFF;
        unsigned long long m = cm;
        while (m) {
            int L = (int)__builtin_ctzll(m); m &= m - 1;
            int hi = __builtin_amdgcn_readlane(__double2hiint(lval), L);
            int lo = __builtin_amdgcn_readlane(__double2loint(lval), L);
            double dv = __hiloint2double(hi, lo);
            int dp = __builtin_amdgcn_readlane(lpay, L);
            if (dv < bv || (dv == bv && dp < bp)) { bv = dv; bp = dp; }
        }
        *oval = bv; *opay = bp;
    }
}

__global__ __launch_bounds__(64) void hungarian_kernel(const float* __restrict__ cost,
                                                       int* __restrict__ assign) {
    const int b = blockIdx.x;
    const int lane = threadIdx.x;
    const float* Cg = cost + (size_t)b * (P_ * T_);

    extern __shared__ char smem[];
    float*  cl = (float*)smem;             // [150*150] f32 cost tile
    double* u  = (double*)(smem + SM_U);   // [151] f64 row duals

    for (int i4 = lane; i4 < (P_ * T_) / 4; i4 += 64)
        ((float4*)cl)[i4] = ((const float4*)Cg)[i4];
    for (int r = lane; r <= P_; r += 64) u[r] = 0.0;
    __syncthreads();

    // per-lane column slots
    const int ja = 1 + lane;            // slot 0: cols 1..64
    const int jb = 65 + lane;           // slot 1: cols 65..128
    const int jc = 129 + lane;          // slot 2: cols 129..150 (lanes 0..21)
    const bool va2 = (jc <= T_);
    const int jcs = va2 ? jc : T_;      // safe address for slot-2 loads

    const double INF = __builtin_inf();

    // ---- Stage A: column reduction with argmin tracking -------------------
    float m0 = cl[ja - 1], m1 = cl[jb - 1], m2 = cl[jcs - 1];
    int i1a = 1, i1b = 1, i1c = 1;      // argmin row per column (first on tie)
    #pragma unroll 4
    for (int r = 2; r <= P_; ++r) {
        int rb_ = (r - 1) * T_;
        float t0 = cl[rb_ + ja - 1], t1 = cl[rb_ + jb - 1], t2 = cl[rb_ + jcs - 1];
        if (t0 < m0) { m0 = t0; i1a = r; }
        if (t1 < m1) { m1 = t1; i1b = r; }
        if (t2 < m2) { m2 = t2; i1c = r; }
    }
    double v0 = (double)m0, v1 = (double)m1, v2 = va2 ? (double)m2 : 0.0;
    int pa = 0, pb = 0, pc = 0;         // p[j]: row matched to col (0 = none)

    // free-row mask: row r <-> lane (r-1)&63, bit (r-1)>>6
    int frm = (lane < 22) ? 7 : 3;

    // greedy column assignment (serial over columns, wave-uniform)
    for (int j = 1; j <= T_; ++j) {
        int sl = (j - 1) >> 6, ol = (j - 1) & 63;
        int i1 = __builtin_amdgcn_readlane(sel3i(sl, i1a, i1b, i1c), ol);
        int rl = (i1 - 1) & 63, rs = (i1 - 1) >> 6;
        int fm = __builtin_amdgcn_readlane(frm, rl);
        if (fm & (1 << rs)) {
            if (lane == ol) {
                if (sl == 0) pa = i1; else if (sl == 1) pb = i1; else pc = i1;
            }
            if (lane == rl) frm &= ~(1 << rs);
        }
    }

    // ---- Stage B: augmenting row reduction (2 passes, chain-capped) -------
    for (int pass = 0; pass < 2; ++pass) {
        for (int irow = 1; irow <= P_; ++irow) {
            {
                int rl = (irow - 1) & 63, rs = (irow - 1) >> 6;
                int fm = __builtin_amdgcn_readlane(frm, rl);
                if (!(fm & (1 << rs))) continue;
            }
            int i = irow;
            for (int guard = 0; guard < CHAIN_CAP; ++guard) {
                int base = (i - 1) * T_ - 1;
                float f0 = cl[base + ja], f1 = cl[base + jb], f2 = cl[base + jcs];
                double r0 = (double)f0 - v0;
                double r1 = (double)f1 - v1;
                double r2 = va2 ? ((double)f2 - v2) : INF;
                // lane-local first/second min with columns (ascending-j ties)
                double lm1, lm2; int lj1, lj2;
                if (r0 <= r1) { lm1 = r0; lj1 = ja; lm2 = r1; lj2 = jb; }
                else          { lm1 = r1; lj1 = jb; lm2 = r0; lj2 = ja; }
                if (r2 < lm1)      { lm2 = lm1; lj2 = lj1; lm1 = r2; lj1 = jc; }
                else if (r2 < lm2) { lm2 = r2; lj2 = jc; }

                double umin; int j1;
                wave_argmin(lm1, lj1, &umin, &j1);
                double s1 = (lj1 == j1) ? lm2 : lm1;
                int    sj = (lj1 == j1) ? lj2 : lj1;
                double usub; int j2;
                wave_argmin(s1, sj, &usub, &j2);

                bool strict = (umin < usub);
                int jt = j1;
                if (strict) {
                    double d = usub - umin;
                    if (lane == ((j1 - 1) & 63)) {
                        int sl = (j1 - 1) >> 6;
                        if (sl == 0) v0 -= d; else if (sl == 1) v1 -= d; else v2 -= d;
                    }
                } else {
                    int sl = (j1 - 1) >> 6, ol = (j1 - 1) & 63;
                    int pj1 = __builtin_amdgcn_readlane(sel3i(sl, pa, pb, pc), ol);
                    if (pj1 != 0) jt = j2;
                }
                int slt = (jt - 1) >> 6, olt = (jt - 1) & 63;
                int k = __builtin_amdgcn_readlane(sel3i(slt, pa, pb, pc), olt);
                // assign i -> jt
                if (lane == olt) {
                    if (slt == 0) pa = i; else if (slt == 1) pb = i; else pc = i;
                }
                if (lane == 0) u[i] = strict ? usub : umin;   // rc[i,jt] = 0
                { int rl = (i - 1) & 63, rs = (i - 1) >> 6;
                  if (lane == rl) frm &= ~(1 << rs); }
                if (k != 0) {
                    int rl = (k - 1) & 63, rs = (k - 1) >> 6;
                    if (lane == rl) frm |= (1 << rs);
                }
                if (k == 0 || !strict) break;   // done or tie-deferred
                i = k;                          // follow bump (capped)
            }
        }
    }

    // ---- Stage C: SAP phases for remaining free rows ----------------------
    for (int i = 1; i <= P_; ++i) {
        {
            int rl = (i - 1) & 63, rs = (i - 1) >> 6;
            int fm = __builtin_amdgcn_readlane(frm, rl);
            if (!(fm & (1 << rs))) continue;
        }
        double mv0 = INF, mv1 = INF, mv2 = INF;
        int w0 = 0, w1 = 0, w2 = 0;
        int um = va2 ? 0 : 4;           // invalid slot2 marked used
        double ua = 0.0, ub = 0.0, uc = 0.0;   // register u of tree rows
        int ra = 0, rb = 0, rc = 0;
        int j0 = 0;
        int i0cur = i;

        double ui0 = u[i];
        double u_i = ui0;
        int base = (i - 1) * T_ - 1;
        float c0 = cl[base + ja];
        float c1 = cl[base + jb];
        float c2 = cl[base + jcs];

        while (true) {
            if (j0 > 0 && lane == ((j0 - 1) & 63)) {
                int sl = (j0 - 1) >> 6;
                if (sl == 0)      { um |= 1; ua = ui0; ra = i0cur; }
                else if (sl == 1) { um |= 2; ub = ui0; rb = i0cur; }
                else              { um |= 4; uc = ui0; rc = i0cur; }
            }

            double cur0 = ((double)c0 - ui0) - v0;
            double cur1 = ((double)c1 - ui0) - v1;
            double cur2 = ((double)c2 - ui0) - v2;
            if (!(um & 1) && cur0 < mv0) { mv0 = cur0; w0 = j0; }
            if (!(um & 2) && cur1 < mv1) { mv1 = cur1; w1 = j0; }
            if (!(um & 4) && cur2 < mv2) { mv2 = cur2; w2 = j0; }

            double bestv = INF; int bestj = 0x7FFFFFFF; int bestp = 0;
            if (!(um & 1))                { bestv = mv0; bestj = ja; bestp = pa; }
            if (!(um & 2) && mv1 < bestv) { bestv = mv1; bestj = jb; bestp = pb; }
            if (!(um & 4) && mv2 < bestv) { bestv = mv2; bestj = jc; bestp = pc; }

            float kf = (float)bestv + 0.0f;
            unsigned key = ord32(kf);
            unsigned x = key;
            DPPMIN(x, 0x111); DPPMIN(x, 0x112); DPPMIN(x, 0x114);
            DPPMIN(x, 0x118); DPPMIN(x, 0x142); DPPMIN(x, 0x143);
            unsigned kmin = (unsigned)__builtin_amdgcn_readlane((int)x, 63);

            unsigned long long cm = __ballot(key == kmin);
            int j1, pj; double delta;
            int pk = (bestp << 8) | (bestj & 0xFF);
            if (__popcll(cm) == 1) {
                int L = (int)__builtin_ctzll(cm);
                int pkw = __builtin_amdgcn_readlane(pk, L);
                j1 = pkw & 0xFF;
                pj = pkw >> 8;
                int hi = __builtin_amdgcn_readlane(__double2hiint(bestv), L);
                int lo = __builtin_amdgcn_readlane(__double2loint(bestv), L);
                delta = __hiloint2double(hi, lo);
            } else {
                double bv = INF; int bj = 0x7FFFFFFF; int bp = 0;
                unsigned long long m = cm;
                while (m) {
                    int L = (int)__builtin_ctzll(m); m &= m - 1;
                    int hi = __builtin_amdgcn_readlane(__double2hiint(bestv), L);
                    int lo = __builtin_amdgcn_readlane(__double2loint(bestv), L);
                    double dv = __hiloint2double(hi, lo);
                    int dj = __builtin_amdgcn_readlane(bestj, L);
                    int dp = __builtin_amdgcn_readlane(bestp, L);
                    if (dv < bv || (dv == bv && dj < bj)) { bv = dv; bj = dj; bp = dp; }
                }
                j1 = bj; pj = bp; delta = bv;
            }

            int pr = (pj > 0) ? pj : 1;
            double ui_n = u[pr];
            int bn = (pr - 1) * T_ - 1;
            float c0n = cl[bn + ja];
            float c1n = cl[bn + jb];
            float c2n = cl[bn + jcs];

            if (um & 1) { v0 -= delta; ua += delta; } else { mv0 -= delta; }
            if (um & 2) { v1 -= delta; ub += delta; } else { mv1 -= delta; }
            if (va2) {
                if (um & 4) { v2 -= delta; uc += delta; } else { mv2 -= delta; }
            }
            u_i += delta;

            i0cur = pj;
            j0 = j1;
            if (pj == 0) break;
            ui0 = ui_n; c0 = c0n; c1 = c1n; c2 = c2n;
        }

        if (um & 1) u[ra] = ua;
        if (um & 2) u[rb] = ub;
        if (va2 && (um & 4)) u[rc] = uc;
        if (lane == 0) u[i] = u_i;

        int jj = j0;
        while (jj != 0) {
            int sj = (jj - 1) >> 6, lj = (jj - 1) & 63;
            int jn = __shfl(sel3i(sj, w0, w1, w2), lj);
            int rown;
            if (jn == 0) rown = i;
            else {
                int sn = (jn - 1) >> 6, ln = (jn - 1) & 63;
                rown = __shfl(sel3i(sn, pa, pb, pc), ln);
            }
            if (lane == lj) {
                if (sj == 0) pa = rown; else if (sj == 1) pb = rown; else pc = rown;
            }
            jj = jn;
        }
    }

    // extract: col j matched to row p[j]-1; perfect matching covers all rows
    assign[b * P_ + (pa - 1)] = ja - 1;
    assign[b * P_ + (pb - 1)] = jb - 1;
    if (va2) assign[b * P_ + (pc - 1)] = jc - 1;
}

// ---------------------------------------------------------------------------
// Kernel 3: per-i partial loss: mean over (b,k) of cost[b, k, assign_i[k]]
// ---------------------------------------------------------------------------
__global__ void gather_kernel(const float* __restrict__ cost,
                              const int* __restrict__ assign,
                              double* __restrict__ partial) {
    const int i = blockIdx.x;
    const int* a = assign + i * P_;
    double s = 0.0;
    for (int idx = threadIdx.x; idx < B_ * P_; idx += blockDim.x) {
        int b = idx / P_;
        int k = idx % P_;
        s += (double)cost[((size_t)b * P_ + k) * T_ + a[k]];
    }
    __shared__ double red[256];
    red[threadIdx.x] = s;
    __syncthreads();
    for (int off = 128; off >= 1; off >>= 1) {
        if (threadIdx.x < off) red[threadIdx.x] += red[threadIdx.x + off];
        __syncthreads();
    }
    if (threadIdx.x == 0) partial[i] = red[0] / (double)(B_ * P_);
}

// ---------------------------------------------------------------------------
// Kernel 4: final sum (deterministic order) -> f32 scalar
// ---------------------------------------------------------------------------
__global__ void finalize_kernel(const double* __restrict__ partial,
                                float* __restrict__ out) {
    if (threadIdx.x == 0 && blockIdx.x == 0) {
        double s = 0.0;
        for (int i = 0; i < B_; ++i) s += partial[i];
        out[0] = (float)s;
    }
}

// ---------------------------------------------------------------------------
extern "C" void kernel_launch(void* const* d_in, const int* in_sizes, int n_in,
                              void* d_out, int out_size, void* d_ws, size_t ws_size,
                              hipStream_t stream) {
    const float* prob   = (const float*)d_in[0];   // [64,150,81]
    const float* pbox   = (const float*)d_in[1];   // [64,150,4]
    const float* labels = (const float*)d_in[2];   // [64,150,5]
    float* out = (float*)d_out;

    char* ws = (char*)d_ws;
    float*  cost    = (float*) ws;                               // 5,760,000 B
    int*    assign  = (int*)   (ws + (size_t)B_ * P_ * T_ * 4);  // 38,400 B
    double* partial = (double*)(ws + (size_t)B_ * P_ * T_ * 4 + (size_t)B_ * P_ * 4);

    const int total = B_ * P_ * T_;
    cost_kernel<<<(total + 255) / 256, 256, 0, stream>>>(prob, pbox, labels, cost);

    hungarian_kernel<<<B_, 64, SM_TOTAL, stream>>>(cost, assign);

    gather_kernel<<<B_, 256, 0, stream>>>(cost, assign, partial);

    finalize_kernel<<<1, 64, 0, stream>>>(partial, out);
}

// Round 7
// 1008.248 us; speedup vs baseline: 2.0479x; 1.0049x over previous
//
#include <hip/hip_runtime.h>
#include <hip/hip_bf16.h>
#include <math.h>

// Problem constants (match reference)
#define B_   64
#define P_   150   // n_pred (rows)
#define T_   150   // n_true (cols)
#define C_   81
#define NOOBJ 80
#define CHAIN_CAP 8   // ARR: max bump-chain steps (R5: unbounded churns; R6: 4 ok; R7: 8)
#define ARR_PASSES 3

// ---------------------------------------------------------------------------
// Kernel 1: cost matrix [B, P, T] in f32
// ---------------------------------------------------------------------------
__global__ void cost_kernel(const float* __restrict__ prob,
                            const float* __restrict__ pbox,
                            const float* __restrict__ labels,
                            float* __restrict__ cost) {
    int idx = blockIdx.x * blockDim.x + threadIdx.x;
    const int total = B_ * P_ * T_;
    if (idx >= total) return;
    int t  = idx % T_;
    int p  = (idx / T_) % P_;
    int b  = idx / (P_ * T_);

    const float* lb5 = labels + ((size_t)b * T_ + t) * 5;
    const float inv = 1.0f / 320.0f;
    float lcx = lb5[0] * inv, lcy = lb5[1] * inv, lw = lb5[2] * inv, lh = lb5[3] * inv;
    int cls = (int)lb5[4];

    const float* pb = pbox + ((size_t)b * P_ + p) * 4;
    float pcx = pb[0], pcy = pb[1], pw = pb[2], ph = pb[3];

    float nll = -logf(prob[((size_t)b * P_ + p) * C_ + cls]);

    float l1 = 0.25f * (fabsf(pcx - lcx) + fabsf(pcy - lcy) +
                        fabsf(pw - lw)   + fabsf(ph - lh));

    float px0 = pcx - 0.5f * pw, py0 = pcy - 0.5f * ph;
    float px1 = pcx + 0.5f * pw, py1 = pcy + 0.5f * ph;
    float lx0 = lcx - 0.5f * lw, ly0 = lcy - 0.5f * lh;
    float lx1 = lcx + 0.5f * lw, ly1 = lcy + 0.5f * lh;

    float ltx = fmaxf(px0, lx0), lty = fmaxf(py0, ly0);
    float rbx = fminf(px1, lx1), rby = fminf(py1, ly1);
    float iw = fmaxf(rbx - ltx, 0.f), ih = fmaxf(rby - lty, 0.f);
    float inter = iw * ih;
    float ap = (px1 - px0) * (py1 - py0);
    float al = (lx1 - lx0) * (ly1 - ly0);
    float un = ap + al - inter;
    float iou = inter / (un + 1e-7f);

    float cx0 = fminf(px0, lx0), cy0 = fminf(py0, ly0);
    float cx1 = fmaxf(px1, lx1), cy1 = fmaxf(py1, ly1);
    float cw = fmaxf(cx1 - cx0, 0.f), ch = fmaxf(cy1 - cy0, 0.f);
    float enc = cw * ch;
    float giou = iou - (enc - un) / (enc + 1e-7f);
    float gl = 1.0f - giou;

    float mask = (cls != NOOBJ) ? 1.0f : 0.0f;
    cost[idx] = nll + (5.0f * l1 + 2.0f * gl) * mask;
}

// ---------------------------------------------------------------------------
// Kernel 2: LAPJV-style Hungarian, one wave per batch, register-resident.
//  Stage A: column reduction + greedy column assignment
//  Stage B: augmenting row reduction, 3 passes, chain cap 8
//  Stage C: shortest-augmenting-path phases for remaining free rows
//  Invariant in every stage: rc[i,j]=c-u[i]-v[j] >= 0 for assigned rows,
//  ==0 on matched edges -> exact optimum -> equals reference (unique optimum
//  for continuous random data; validated absmax=0 in R2-R6).
//  All argmin keys are >= 0 (dual feasibility), so raw f32 bit patterns are
//  order-monotone: DPP min on raw bits, exact f64 resolve on f32-key ties.
// ---------------------------------------------------------------------------
#define SM_U      (P_ * T_ * 4)           // after 90000 B cost tile (8B aligned)
#define SM_TOTAL  (SM_U + 152 * 8)

#define DPPMIN(x, ctrl)                                                          \
    do {                                                                         \
        unsigned _t = (unsigned)__builtin_amdgcn_update_dpp(                     \
            (int)(x), (int)(x), (ctrl), 0xF, 0xF, false);                        \
        (x) = (_t < (x)) ? _t : (x);                                             \
    } while (0)

__device__ __forceinline__ int sel3i(int s, int a, int b, int c) {
    return s == 0 ? a : (s == 1 ? b : c);
}

// wave-wide exact f64 argmin (values >= 0); payload tie-break = smaller pay
__device__ __forceinline__ void wave_argmin(double lval, int lpay,
                                            double* oval, int* opay) {
    unsigned key = __float_as_uint((float)lval);   // >=0: bits are monotone
    unsigned x = key;
    DPPMIN(x, 0x111); DPPMIN(x, 0x112); DPPMIN(x, 0x114);
    DPPMIN(x, 0x118); DPPMIN(x, 0x142); DPPMIN(x, 0x143);
    unsigned kmin = (unsigned)__builtin_amdgcn_readlane((int)x, 63);
    unsigned long long cm = __ballot(key == kmin);
    if (__popcll(cm) == 1) {
        int L = (int)__builtin_ctzll(cm);
        int hi = __builtin_amdgcn_readlane(__double2hiint(lval), L);
        int lo = __builtin_amdgcn_readlane(__double2loint(lval), L);
        *oval = __hiloint2double(hi, lo);
        *opay = __builtin_amdgcn_readlane(lpay, L);
    } else {
        double bv = __builtin_inf(); int bp = 0x7FFFFFFF;
        unsigned long long m = cm;
        while (m) {
            int L = (int)__builtin_ctzll(m); m &= m - 1;
            int hi = __builtin_amdgcn_readlane(__double2hiint(lval), L);
            int lo = __builtin_amdgcn_readlane(__double2loint(lval), L);
            double dv = __hiloint2double(hi, lo);
            int dp = __builtin_amdgcn_readlane(lpay, L);
            if (dv < bv || (dv == bv && dp < bp)) { bv = dv; bp = dp; }
        }
        *oval = bv; *opay = bp;
    }
}

__global__ __launch_bounds__(64) void hungarian_kernel(const float* __restrict__ cost,
                                                       int* __restrict__ assign) {
    const int b = blockIdx.x;
    const int lane = threadIdx.x;
    const float* Cg = cost + (size_t)b * (P_ * T_);

    extern __shared__ char smem[];
    float*  cl = (float*)smem;             // [150*150] f32 cost tile
    double* u  = (double*)(smem + SM_U);   // [151] f64 row duals

    for (int i4 = lane; i4 < (P_ * T_) / 4; i4 += 64)
        ((float4*)cl)[i4] = ((const float4*)Cg)[i4];
    for (int r = lane; r <= P_; r += 64) u[r] = 0.0;
    __syncthreads();

    // per-lane column slots
    const int ja = 1 + lane;            // slot 0: cols 1..64
    const int jb = 65 + lane;           // slot 1: cols 65..128
    const int jc = 129 + lane;          // slot 2: cols 129..150 (lanes 0..21)
    const bool va2 = (jc <= T_);
    const int jcs = va2 ? jc : T_;      // safe address for slot-2 loads

    const double INF = __builtin_inf();

    // ---- Stage A: column reduction with argmin tracking -------------------
    float m0 = cl[ja - 1], m1 = cl[jb - 1], m2 = cl[jcs - 1];
    int i1a = 1, i1b = 1, i1c = 1;      // argmin row per column (first on tie)
    #pragma unroll 4
    for (int r = 2; r <= P_; ++r) {
        int rb_ = (r - 1) * T_;
        float t0 = cl[rb_ + ja - 1], t1 = cl[rb_ + jb - 1], t2 = cl[rb_ + jcs - 1];
        if (t0 < m0) { m0 = t0; i1a = r; }
        if (t1 < m1) { m1 = t1; i1b = r; }
        if (t2 < m2) { m2 = t2; i1c = r; }
    }
    double v0 = (double)m0, v1 = (double)m1, v2 = va2 ? (double)m2 : 0.0;
    int pa = 0, pb = 0, pc = 0;         // p[j]: row matched to col (0 = none)

    // free-row mask: row r <-> lane (r-1)&63, bit (r-1)>>6
    int frm = (lane < 22) ? 7 : 3;

    // greedy column assignment (serial over columns, wave-uniform)
    for (int j = 1; j <= T_; ++j) {
        int sl = (j - 1) >> 6, ol = (j - 1) & 63;
        int i1 = __builtin_amdgcn_readlane(sel3i(sl, i1a, i1b, i1c), ol);
        int rl = (i1 - 1) & 63, rs = (i1 - 1) >> 6;
        int fm = __builtin_amdgcn_readlane(frm, rl);
        if (fm & (1 << rs)) {
            if (lane == ol) {
                if (sl == 0) pa = i1; else if (sl == 1) pb = i1; else pc = i1;
            }
            if (lane == rl) frm &= ~(1 << rs);
        }
    }

    // ---- Stage B: augmenting row reduction (passes, chain-capped) ---------
    for (int pass = 0; pass < ARR_PASSES; ++pass) {
        for (int irow = 1; irow <= P_; ++irow) {
            {
                int rl = (irow - 1) & 63, rs = (irow - 1) >> 6;
                int fm = __builtin_amdgcn_readlane(frm, rl);
                if (!(fm & (1 << rs))) continue;
            }
            int i = irow;
            for (int guard = 0; guard < CHAIN_CAP; ++guard) {
                int base = (i - 1) * T_ - 1;
                float f0 = cl[base + ja], f1 = cl[base + jb], f2 = cl[base + jcs];
                double r0 = (double)f0 - v0;
                double r1 = (double)f1 - v1;
                double r2 = va2 ? ((double)f2 - v2) : INF;
                // lane-local first/second min with columns (ascending-j ties)
                double lm1, lm2; int lj1, lj2;
                if (r0 <= r1) { lm1 = r0; lj1 = ja; lm2 = r1; lj2 = jb; }
                else          { lm1 = r1; lj1 = jb; lm2 = r0; lj2 = ja; }
                if (r2 < lm1)      { lm2 = lm1; lj2 = lj1; lm1 = r2; lj1 = jc; }
                else if (r2 < lm2) { lm2 = r2; lj2 = jc; }

                double umin; int j1;
                wave_argmin(lm1, lj1, &umin, &j1);
                double s1 = (lj1 == j1) ? lm2 : lm1;
                int    sj = (lj1 == j1) ? lj2 : lj1;
                double usub; int j2;
                wave_argmin(s1, sj, &usub, &j2);

                bool strict = (umin < usub);
                int jt = j1;
                if (strict) {
                    double d = usub - umin;
                    if (lane == ((j1 - 1) & 63)) {
                        int sl = (j1 - 1) >> 6;
                        if (sl == 0) v0 -= d; else if (sl == 1) v1 -= d; else v2 -= d;
                    }
                } else {
                    int sl = (j1 - 1) >> 6, ol = (j1 - 1) & 63;
                    int pj1 = __builtin_amdgcn_readlane(sel3i(sl, pa, pb, pc), ol);
                    if (pj1 != 0) jt = j2;
                }
                int slt = (jt - 1) >> 6, olt = (jt - 1) & 63;
                int k = __builtin_amdgcn_readlane(sel3i(slt, pa, pb, pc), olt);
                // assign i -> jt
                if (lane == olt) {
                    if (slt == 0) pa = i; else if (slt == 1) pb = i; else pc = i;
                }
                if (lane == 0) u[i] = strict ? usub : umin;   // rc[i,jt] = 0
                { int rl = (i - 1) & 63, rs = (i - 1) >> 6;
                  if (lane == rl) frm &= ~(1 << rs); }
                if (k != 0) {
                    int rl = (k - 1) & 63, rs = (k - 1) >> 6;
                    if (lane == rl) frm |= (1 << rs);
                }
                if (k == 0 || !strict) break;   // done or tie-deferred
                i = k;                          // follow bump (capped)
            }
        }
    }

    // ---- Stage C: SAP phases for remaining free rows ----------------------
    for (int i = 1; i <= P_; ++i) {
        {
            int rl = (i - 1) & 63, rs = (i - 1) >> 6;
            int fm = __builtin_amdgcn_readlane(frm, rl);
            if (!(fm & (1 << rs))) continue;
        }
        double mv0 = INF, mv1 = INF, mv2 = INF;
        int w0 = 0, w1 = 0, w2 = 0;
        int um = va2 ? 0 : 4;           // invalid slot2 marked used
        double ua = 0.0, ub = 0.0, uc = 0.0;   // register u of tree rows
        int ra = 0, rb = 0, rc = 0;
        int j0 = 0;
        int i0cur = i;

        double ui0 = u[i];
        double u_i = ui0;
        int base = (i - 1) * T_ - 1;
        float c0 = cl[base + ja];
        float c1 = cl[base + jb];
        float c2 = cl[base + jcs];

        while (true) {
            if (j0 > 0 && lane == ((j0 - 1) & 63)) {
                int sl = (j0 - 1) >> 6;
                if (sl == 0)      { um |= 1; ua = ui0; ra = i0cur; }
                else if (sl == 1) { um |= 2; ub = ui0; rb = i0cur; }
                else              { um |= 4; uc = ui0; rc = i0cur; }
            }

            double cur0 = ((double)c0 - ui0) - v0;
            double cur1 = ((double)c1 - ui0) - v1;
            double cur2 = ((double)c2 - ui0) - v2;
            if (!(um & 1) && cur0 < mv0) { mv0 = cur0; w0 = j0; }
            if (!(um & 2) && cur1 < mv1) { mv1 = cur1; w1 = j0; }
            if (!(um & 4) && cur2 < mv2) { mv2 = cur2; w2 = j0; }

            double bestv = INF; int bestj = 0x7FFFFFFF; int bestp = 0;
            if (!(um & 1))                { bestv = mv0; bestj = ja; bestp = pa; }
            if (!(um & 2) && mv1 < bestv) { bestv = mv1; bestj = jb; bestp = pb; }
            if (!(um & 4) && mv2 < bestv) { bestv = mv2; bestj = jc; bestp = pc; }

            unsigned key = __float_as_uint((float)bestv);  // >=0: monotone bits
            unsigned x = key;
            DPPMIN(x, 0x111); DPPMIN(x, 0x112); DPPMIN(x, 0x114);
            DPPMIN(x, 0x118); DPPMIN(x, 0x142); DPPMIN(x, 0x143);
            unsigned kmin = (unsigned)__builtin_amdgcn_readlane((int)x, 63);

            unsigned long long cm = __ballot(key == kmin);
            int j1, pj; double delta;
            int pk = (bestp << 8) | (bestj & 0xFF);
            if (__popcll(cm) == 1) {
                int L = (int)__builtin_ctzll(cm);
                int pkw = __builtin_amdgcn_readlane(pk, L);
                j1 = pkw & 0xFF;
                pj = pkw >> 8;
                int hi = __builtin_amdgcn_readlane(__double2hiint(bestv), L);
                int lo = __builtin_amdgcn_readlane(__double2loint(bestv), L);
                delta = __hiloint2double(hi, lo);
            } else {
                double bv = INF; int bj = 0x7FFFFFFF; int bp = 0;
                unsigned long long m = cm;
                while (m) {
                    int L = (int)__builtin_ctzll(m); m &= m - 1;
                    int hi = __builtin_amdgcn_readlane(__double2hiint(bestv), L);
                    int lo = __builtin_amdgcn_readlane(__double2loint(bestv), L);
                    double dv = __hiloint2double(hi, lo);
                    int dj = __builtin_amdgcn_readlane(bestj, L);
                    int dp = __builtin_amdgcn_readlane(bestp, L);
                    if (dv < bv || (dv == bv && dj < bj)) { bv = dv; bj = dj; bp = dp; }
                }
                j1 = bj; pj = bp; delta = bv;
            }

            int pr = (pj > 0) ? pj : 1;
            double ui_n = u[pr];
            int bn = (pr - 1) * T_ - 1;
            float c0n = cl[bn + ja];
            float c1n = cl[bn + jb];
            float c2n = cl[bn + jcs];

            if (um & 1) { v0 -= delta; ua += delta; } else { mv0 -= delta; }
            if (um & 2) { v1 -= delta; ub += delta; } else { mv1 -= delta; }
            if (va2) {
                if (um & 4) { v2 -= delta; uc += delta; } else { mv2 -= delta; }
            }
            u_i += delta;

            i0cur = pj;
            j0 = j1;
            if (pj == 0) break;
            ui0 = ui_n; c0 = c0n; c1 = c1n; c2 = c2n;
        }

        if (um & 1) u[ra] = ua;
        if (um & 2) u[rb] = ub;
        if (va2 && (um & 4)) u[rc] = uc;
        if (lane == 0) u[i] = u_i;

        int jj = j0;
        while (jj != 0) {
            int sj = (jj - 1) >> 6, lj = (jj - 1) & 63;
            int jn = __shfl(sel3i(sj, w0, w1, w2), lj);
            int rown;
            if (jn == 0) rown = i;
            else {
                int sn = (jn - 1) >> 6, ln = (jn - 1) & 63;
                rown = __shfl(sel3i(sn, pa, pb, pc), ln);
            }
            if (lane == lj) {
                if (sj == 0) pa = rown; else if (sj == 1) pb = rown; else pc = rown;
            }
            jj = jn;
        }
    }

    // extract: col j matched to row p[j]-1; perfect matching covers all rows
    assign[b * P_ + (pa - 1)] = ja - 1;
    assign[b * P_ + (pb - 1)] = jb - 1;
    if (va2) assign[b * P_ + (pc - 1)] = jc - 1;
}

// ---------------------------------------------------------------------------
// Kernel 3: per-i partial loss: mean over (b,k) of cost[b, k, assign_i[k]]
// ---------------------------------------------------------------------------
__global__ void gather_kernel(const float* __restrict__ cost,
                              const int* __restrict__ assign,
                              double* __restrict__ partial) {
    const int i = blockIdx.x;
    const int* a = assign + i * P_;
    double s = 0.0;
    for (int idx = threadIdx.x; idx < B_ * P_; idx += blockDim.x) {
        int b = idx / P_;
        int k = idx % P_;
        s += (double)cost[((size_t)b * P_ + k) * T_ + a[k]];
    }
    __shared__ double red[256];
    red[threadIdx.x] = s;
    __syncthreads();
    for (int off = 128; off >= 1; off >>= 1) {
        if (threadIdx.x < off) red[threadIdx.x] += red[threadIdx.x + off];
        __syncthreads();
    }
    if (threadIdx.x == 0) partial[i] = red[0] / (double)(B_ * P_);
}

// ---------------------------------------------------------------------------
// Kernel 4: final sum (deterministic order) -> f32 scalar
// ---------------------------------------------------------------------------
__global__ void finalize_kernel(const double* __restrict__ partial,
                                float* __restrict__ out) {
    if (threadIdx.x == 0 && blockIdx.x == 0) {
        double s = 0.0;
        for (int i = 0; i < B_; ++i) s += partial[i];
        out[0] = (float)s;
    }
}

// ---------------------------------------------------------------------------
extern "C" void kernel_launch(void* const* d_in, const int* in_sizes, int n_in,
                              void* d_out, int out_size, void* d_ws, size_t ws_size,
                              hipStream_t stream) {
    const float* prob   = (const float*)d_in[0];   // [64,150,81]
    const float* pbox   = (const float*)d_in[1];   // [64,150,4]
    const float* labels = (const float*)d_in[2];   // [64,150,5]
    float* out = (float*)d_out;

    char* ws = (char*)d_ws;
    float*  cost    = (float*) ws;                               // 5,760,000 B
    int*    assign  = (int*)   (ws + (size_t)B_ * P_ * T_ * 4);  // 38,400 B
    double* partial = (double*)(ws + (size_t)B_ * P_ * T_ * 4 + (size_t)B_ * P_ * 4);

    const int total = B_ * P_ * T_;
    cost_kernel<<<(total + 255) / 256, 256, 0, stream>>>(prob, pbox, labels, cost);

    hungarian_kernel<<<B_, 64, SM_TOTAL, stream>>>(cost, assign);

    gather_kernel<<<B_, 256, 0, stream>>>(cost, assign, partial);

    finalize_kernel<<<1, 64, 0, stream>>>(partial, out);
}